// Round 5
// baseline (552.357 us; speedup 1.0000x reference)
//
#include <hip/hip_runtime.h>
#include <hip/hip_bf16.h>
#include <math.h>

#define H 128
#define N_REL 4
#define SB 64   // scan blocks per relation

typedef float f32x4 __attribute__((ext_vector_type(4)));
typedef __bf16 bf16x8 __attribute__((ext_vector_type(8)));

__device__ __forceinline__ unsigned short f2bf(float f) {
    return __builtin_bit_cast(unsigned short, (__bf16)f);
}
__device__ __forceinline__ void acc2(unsigned u, float& a, float& b) {
    union { unsigned u; float f; } x, y;
    x.u = u << 16; y.u = u & 0xffff0000u;
    a += x.f; b += y.f;
}
__device__ __forceinline__ float bflo(unsigned u) {
    union { unsigned u; float f; } x; x.u = u << 16; return x.f;
}
__device__ __forceinline__ float bfhi(unsigned u) {
    union { unsigned u; float f; } x; x.u = u & 0xffff0000u; return x.f;
}

// ---------------- CSR build: counts (all relations, one launch) ----------------
__global__ __launch_bounds__(256) void k_count_all(
    const int* __restrict__ s0, const int* __restrict__ s1,
    const int* __restrict__ s2, const int* __restrict__ s3,
    int4 E, int4 boff, int* __restrict__ cnt_all, int n)
{
    int b = blockIdx.x;
    const int* src; int Er, rel;
    if (b < boff.y)      { rel = 0; src = s0; Er = E.x; }
    else if (b < boff.z) { rel = 1; src = s1; Er = E.y; b -= boff.y; }
    else if (b < boff.w) { rel = 2; src = s2; Er = E.z; b -= boff.z; }
    else                 { rel = 3; src = s3; Er = E.w; b -= boff.w; }
    int e = b * 256 + threadIdx.x;
    if (e < Er) atomicAdd(&cnt_all[(size_t)rel * n + src[Er + e]], 1);
}

__global__ __launch_bounds__(256) void k_scan1(const int* __restrict__ cnt_all, int n,
                                               int* __restrict__ partial)
{
    int rel = blockIdx.x >> 6, blk = blockIdx.x & (SB - 1);
    int chunk = (n + SB - 1) / SB;
    int lo = blk * chunk, hi = min(lo + chunk, n);
    const int* cnt = cnt_all + (size_t)rel * n;
    int s = 0;
    for (int i = lo + threadIdx.x; i < hi; i += 256) s += cnt[i];
    __shared__ int sh[256];
    sh[threadIdx.x] = s; __syncthreads();
    for (int d = 128; d; d >>= 1) {
        if (threadIdx.x < d) sh[threadIdx.x] += sh[threadIdx.x + d];
        __syncthreads();
    }
    if (threadIdx.x == 0) partial[rel * SB + blk] = sh[0];
}

__global__ __launch_bounds__(256) void k_scan2(int* __restrict__ partial,
                                               int* __restrict__ rowptr_all, int n, int4 Etot)
{
    int rel = threadIdx.x >> 6, lane = threadIdx.x & 63;
    int v = partial[rel * SB + lane];
    int inc = v;
    for (int d = 1; d < 64; d <<= 1) {
        int t = __shfl_up(inc, d);
        if (lane >= d) inc += t;
    }
    partial[rel * SB + lane] = inc - v;
    if (lane == 0) {
        int E = (rel == 0) ? Etot.x : (rel == 1) ? Etot.y : (rel == 2) ? Etot.z : Etot.w;
        rowptr_all[(size_t)rel * (n + 1) + n] = E;
    }
}

// recip = (c>0) ? 1/c : 0   (0 doubles as "has edges" mask)
__global__ __launch_bounds__(256) void k_scan3(const int* __restrict__ cnt_all,
                                               const int* __restrict__ partial,
                                               int* __restrict__ rowptr_all,
                                               int* __restrict__ cursor_all,
                                               float* __restrict__ recip_all, int n)
{
    int rel = blockIdx.x >> 6, blk = blockIdx.x & (SB - 1);
    int chunk = (n + SB - 1) / SB;
    int lo = blk * chunk, hi = min(lo + chunk, n);
    const int* cnt = cnt_all + (size_t)rel * n;
    int per = (chunk + 255) >> 8;
    int tlo = min(lo + threadIdx.x * per, hi);
    int thi = min(tlo + per, hi);
    int s = 0;
    for (int i = tlo; i < thi; ++i) s += cnt[i];
    __shared__ int sh[256];
    sh[threadIdx.x] = s; __syncthreads();
    for (int d = 1; d < 256; d <<= 1) {
        int t = (threadIdx.x >= d) ? sh[threadIdx.x - d] : 0;
        __syncthreads();
        sh[threadIdx.x] += t;
        __syncthreads();
    }
    int run = partial[rel * SB + blk] + sh[threadIdx.x] - s;
    int* rowptr = rowptr_all + (size_t)rel * (n + 1);
    int* cursor = cursor_all + (size_t)rel * n;
    float* recip = recip_all + (size_t)rel * n;
    for (int i = tlo; i < thi; ++i) {
        int c = cnt[i];
        rowptr[i] = run;
        cursor[i] = run;
        recip[i] = (c > 0) ? 1.0f / (float)c : 0.0f;
        run += c;
    }
}

__global__ __launch_bounds__(256) void k_fill_all(
    const int* __restrict__ s0, const int* __restrict__ s1,
    const int* __restrict__ s2, const int* __restrict__ s3,
    int4 E, int4 boff, int* __restrict__ cursor_all,
    int* __restrict__ c0, int* __restrict__ c1,
    int* __restrict__ c2, int* __restrict__ c3, int n)
{
    int b = blockIdx.x;
    const int* src; int Er, rel; int* colp;
    if (b < boff.y)      { rel = 0; src = s0; Er = E.x; colp = c0; }
    else if (b < boff.z) { rel = 1; src = s1; Er = E.y; colp = c1; b -= boff.y; }
    else if (b < boff.w) { rel = 2; src = s2; Er = E.z; colp = c2; b -= boff.z; }
    else                 { rel = 3; src = s3; Er = E.w; colp = c3; b -= boff.w; }
    int e = b * 256 + threadIdx.x;
    if (e >= Er) return;
    int t = src[Er + e];
    int slot = atomicAdd(&cursor_all[(size_t)rel * n + t], 1);
    colp[slot] = src[e];
}

// ---------------- MFMA encoder for x_int (K=32, one MFMA step) ----------------
__global__ __launch_bounds__(256) void k_encmfma(const float* __restrict__ x,
                                                 const float* __restrict__ W,
                                                 const float* __restrict__ b,
                                                 unsigned short* __restrict__ h, int n)
{
    __shared__ __align__(16) char WB[128 * 80];
    int tid = threadIdx.x;
    {
        int c = tid & 127, khalf = tid >> 7;
        for (int kk = 0; kk < 16; ++kk) {
            int k = khalf * 16 + kk;
            *(unsigned short*)(WB + c * 80 + k * 2) = f2bf(W[(size_t)k * H + c]);
        }
    }
    int lane = tid & 63, wv = tid >> 6;
    int r16 = lane & 15, kgrp = lane >> 4;
    int rowbase = blockIdx.x * 64 + wv * 16;
    int arow = rowbase + r16; if (arow >= n) arow = n - 1;
    const float* xr = x + (size_t)arow * 32 + kgrp * 8;
    float4 xa = *(const float4*)xr, xb = *(const float4*)(xr + 4);
    bf16x8 af;
    af[0] = (__bf16)xa.x; af[1] = (__bf16)xa.y; af[2] = (__bf16)xa.z; af[3] = (__bf16)xa.w;
    af[4] = (__bf16)xb.x; af[5] = (__bf16)xb.y; af[6] = (__bf16)xb.z; af[7] = (__bf16)xb.w;
    __syncthreads();
#pragma unroll
    for (int ct = 0; ct < 8; ++ct) {
        int c = ct * 16 + r16;
        bf16x8 bf = *(const bf16x8*)(WB + c * 80 + kgrp * 16);
        f32x4 acc = { 0.f, 0.f, 0.f, 0.f };
        acc = __builtin_amdgcn_mfma_f32_16x16x32_bf16(af, bf, acc, 0, 0, 0);
        float bb = b[c];
#pragma unroll
        for (int i = 0; i < 4; ++i) {
            int grow = rowbase + kgrp * 4 + i;
            if (grow < n) h[(size_t)grow * H + c] = f2bf(acc[i] + bb);
        }
    }
}

// ---------------- static relations: gather-mean of RAW x (one launch) ----------------
template<int D>
__device__ __forceinline__ void aggx_body(const float* __restrict__ x,
                                          const int* __restrict__ rowptr,
                                          const int* __restrict__ col,
                                          const float* __restrict__ recip,
                                          float* __restrict__ out, int n, int b)
{
    const int rpb = 256 / D;
    int row = b * rpb + (int)(threadIdx.x / D);
    if (row >= n) return;
    int d = threadIdx.x & (D - 1);
    int beg = rowptr[row], end = rowptr[row + 1];
    float s0 = 0.f, s1 = 0.f;
    int e = beg;
    for (; e + 2 <= end; e += 2) {
        s0 += x[(size_t)col[e] * D + d];
        s1 += x[(size_t)col[e + 1] * D + d];
    }
    if (e < end) s0 += x[(size_t)col[e] * D + d];
    out[(size_t)row * D + d] = (s0 + s1) * recip[row];
}

__global__ __launch_bounds__(256) void k_aggx_all(
    const float* __restrict__ xL, const float* __restrict__ xS, const float* __restrict__ xI,
    const int* __restrict__ rowptr_all,
    const int* __restrict__ cL, const int* __restrict__ cS, const int* __restrict__ cI,
    const float* __restrict__ recip_all,
    float* __restrict__ XL, float* __restrict__ XS, float* __restrict__ XI,
    int n, int BL, int BS)
{
    int b = blockIdx.x;
    if (b < BL)
        aggx_body<16>(xL, rowptr_all + (size_t)(n + 1), cL, recip_all + (size_t)n, XL, n, b);
    else if (b < BL + BS)
        aggx_body<8>(xS, rowptr_all + 2 * (size_t)(n + 1), cS, recip_all + 2 * (size_t)n, XS, n, b - BL);
    else
        aggx_body<8>(xI, rowptr_all + 3 * (size_t)(n + 1), cI, recip_all + 3 * (size_t)n, XI, n, b - BL - BS);
}

// ---------------- stat(bf16) = XL@WL + XS@WS + XI@WI + masked biases ----------------
__global__ __launch_bounds__(256) void k_stat(
    const float* __restrict__ XL, const float* __restrict__ XS, const float* __restrict__ XI,
    const float* __restrict__ WL, const float* __restrict__ WSn, const float* __restrict__ WI,
    const float* __restrict__ bL, const float* __restrict__ bS, const float* __restrict__ bI,
    const float* __restrict__ rL, const float* __restrict__ rS, const float* __restrict__ rI,
    unsigned short* __restrict__ statb, int n)
{
    __shared__ float Wc[32][128];
    __shared__ float xs[8][32];
    int t = threadIdx.x;
    for (int i = t; i < 16 * 128; i += 256) Wc[i >> 7][i & 127] = WL[i];
    for (int i = t; i < 8 * 128; i += 256)  Wc[16 + (i >> 7)][i & 127] = WSn[i];
    for (int i = t; i < 8 * 128; i += 256)  Wc[24 + (i >> 7)][i & 127] = WI[i];
    {
        int rr = t >> 5, k = t & 31;
        int rrow = blockIdx.x * 8 + rr; if (rrow >= n) rrow = n - 1;
        float v;
        if (k < 16)      v = XL[(size_t)rrow * 16 + k];
        else if (k < 24) v = XS[(size_t)rrow * 8 + (k - 16)];
        else             v = XI[(size_t)rrow * 8 + (k - 24)];
        xs[rr][k] = v;
    }
    __syncthreads();
    int rl = t >> 5, c4 = (t & 31) << 2;
    int row = blockIdx.x * 8 + rl;
    float a0 = 0.f, a1 = 0.f, a2 = 0.f, a3 = 0.f;
#pragma unroll
    for (int k = 0; k < 32; ++k) {
        float xv = xs[rl][k];
        a0 += xv * Wc[k][c4 + 0]; a1 += xv * Wc[k][c4 + 1];
        a2 += xv * Wc[k][c4 + 2]; a3 += xv * Wc[k][c4 + 3];
    }
    if (row < n) {
        float mL = (rL[row] > 0.f) ? 1.f : 0.f;
        float mS = (rS[row] > 0.f) ? 1.f : 0.f;
        float mI = (rI[row] > 0.f) ? 1.f : 0.f;
        ushort4 res;
        res.x = f2bf(a0 + mL * bL[c4 + 0] + mS * bS[c4 + 0] + mI * bI[c4 + 0]);
        res.y = f2bf(a1 + mL * bL[c4 + 1] + mS * bS[c4 + 1] + mI * bI[c4 + 1]);
        res.z = f2bf(a2 + mL * bL[c4 + 2] + mS * bS[c4 + 2] + mI * bI[c4 + 2]);
        res.w = f2bf(a3 + mL * bL[c4 + 3] + mS * bS[c4 + 3] + mI * bI[c4 + 3]);
        *(ushort4*)(statb + (size_t)row * H + c4) = res;
    }
}

// ---------------- fused layer: gather agg into LDS, then MFMA + ELU ----------------
// block = 256 thr, 64 rows. LDS: BT 64KB (weights) + AGG 16KB = 80KB -> 2 blocks/CU.
template<int LAST>
__global__ __launch_bounds__(256) void k_flayer(
    const unsigned short* __restrict__ hb,
    const int* __restrict__ rowptr, const int* __restrict__ col,
    const float* __restrict__ recip, const unsigned short* __restrict__ statb,
    const float* __restrict__ Ws, const float* __restrict__ Wr,
    const float* __restrict__ bias,
    unsigned short* __restrict__ hbout, float* __restrict__ fout, int n)
{
    __shared__ __align__(16) char BT[128 * 256 * 2];
    __shared__ __align__(16) char AGG[64 * 256];

    int tid = threadIdx.x;
    int rowbase = blockIdx.x * 64;

    // ---- BT[c][k] = W[k][c] bf16, swizzle byte ^= (c&7)<<4 ----
    {
        int c = tid & 127, half = tid >> 7;
        for (int kc = half; kc < 32; kc += 2) {
            int kk0 = kc * 8;
            const float* Wsrc = (kk0 < 128) ? (Ws + (size_t)kk0 * H + c)
                                            : (Wr + (size_t)(kk0 - 128) * H + c);
            bf16x8 pack;
#pragma unroll
            for (int j = 0; j < 8; ++j) pack[j] = (__bf16)Wsrc[(size_t)j * H];
            int woff = c * 512 + ((kc * 16) ^ ((c & 7) << 4));
            *(bf16x8*)(BT + woff) = pack;
        }
    }

    // ---- gather phase: agg rows into AGG LDS (8 passes x 8 rows) ----
    {
        int sub = tid >> 5;              // row-in-pass
        int q = (tid & 31) << 2;         // 4 bf16 dims per lane
        for (int pass = 0; pass < 8; ++pass) {
            int lr = pass * 8 + sub;
            int row = rowbase + lr; if (row >= n) row = n - 1;
            int beg = rowptr[row], end = rowptr[row + 1];
            float a0 = 0.f, a1 = 0.f, a2 = 0.f, a3 = 0.f;
            int e = beg;
            for (; e + 4 <= end; e += 4) {
                int s0 = col[e], s1 = col[e + 1], s2 = col[e + 2], s3 = col[e + 3];
                uint2 v0 = *(const uint2*)(hb + (size_t)s0 * H + q);
                uint2 v1 = *(const uint2*)(hb + (size_t)s1 * H + q);
                uint2 v2 = *(const uint2*)(hb + (size_t)s2 * H + q);
                uint2 v3 = *(const uint2*)(hb + (size_t)s3 * H + q);
                acc2(v0.x, a0, a1); acc2(v0.y, a2, a3);
                acc2(v1.x, a0, a1); acc2(v1.y, a2, a3);
                acc2(v2.x, a0, a1); acc2(v2.y, a2, a3);
                acc2(v3.x, a0, a1); acc2(v3.y, a2, a3);
            }
            for (; e < end; ++e) {
                uint2 v0 = *(const uint2*)(hb + (size_t)col[e] * H + q);
                acc2(v0.x, a0, a1); acc2(v0.y, a2, a3);
            }
            float r = recip[row];
            uint2 sv = *(const uint2*)(statb + (size_t)row * H + q);
            ushort4 w;
            w.x = f2bf(a0 * r + bflo(sv.x)); w.y = f2bf(a1 * r + bfhi(sv.x));
            w.z = f2bf(a2 * r + bflo(sv.y)); w.w = f2bf(a3 * r + bfhi(sv.y));
            int woff = (lr * 256 + (q << 1)) ^ ((lr & 7) << 4);
            *(ushort4*)(AGG + woff) = w;
        }
    }

    int lane = tid & 63, wv = tid >> 6;
    int r16 = lane & 15, kgrp = lane >> 4;
    int lr = wv * 16 + r16;
    int arow = rowbase + lr; if (arow >= n) arow = n - 1;

    // h-half A-fragments (global) can issue before the barrier
    bf16x8 afrag[8];
#pragma unroll
    for (int ks = 0; ks < 4; ++ks) {
        int k0 = ks * 32 + kgrp * 8;
        afrag[ks] = *(const bf16x8*)(hb + (size_t)arow * H + k0);
    }
    __syncthreads();
    // agg-half from LDS
#pragma unroll
    for (int ks = 4; ks < 8; ++ks) {
        int k0 = (ks - 4) * 32 + kgrp * 8;
        int off = (lr * 256 + k0 * 2) ^ ((lr & 7) << 4);
        afrag[ks] = *(const bf16x8*)(AGG + off);
    }

#pragma unroll
    for (int ct = 0; ct < 8; ++ct) {
        int c = ct * 16 + r16;
        f32x4 acc = { 0.f, 0.f, 0.f, 0.f };
#pragma unroll
        for (int ks = 0; ks < 8; ++ks) {
            int kbyte = ks * 64 + kgrp * 16;
            int off = c * 512 + (kbyte ^ ((c & 7) << 4));
            bf16x8 bfrag = *(const bf16x8*)(BT + off);
            acc = __builtin_amdgcn_mfma_f32_16x16x32_bf16(afrag[ks], bfrag, acc, 0, 0, 0);
        }
        float bb = bias[c];
#pragma unroll
        for (int i = 0; i < 4; ++i) {
            int grow = rowbase + wv * 16 + kgrp * 4 + i;
            if (grow < n) {
                float v = acc[i] + bb;
                v = (v > 0.f) ? v : (expf(v) - 1.f);
                if (LAST) fout[(size_t)grow * H + c] = v;
                else      hbout[(size_t)grow * H + c] = f2bf(v);
            }
        }
    }
}

extern "C" void kernel_launch(void* const* d_in, const int* in_sizes, int n_in,
                              void* d_out, int out_size, void* d_ws, size_t ws_size,
                              hipStream_t stream)
{
    const float* x_int  = (const float*)d_in[0];
    const float* x_lane = (const float*)d_in[1];
    const float* x_sens = (const float*)d_in[2];
    const float* x_inj  = (const float*)d_in[3];
    const int*   e_sp   = (const int*)d_in[4];
    const int*   e_fl   = (const int*)d_in[5];
    const int*   e_fs   = (const int*)d_in[6];
    const int*   e_in   = (const int*)d_in[7];
    const float* W_int  = (const float*)d_in[8];
    const float* b_int  = (const float*)d_in[9];
    const float* W_lane = (const float*)d_in[10];
    const float* b_lane = (const float*)d_in[11];
    const float* W_sens = (const float*)d_in[12];
    const float* b_sens = (const float*)d_in[13];
    const float* W_inj  = (const float*)d_in[14];
    const float* b_inj  = (const float*)d_in[15];
    const float* self_W = (const float*)d_in[16];
    const float* self_b = (const float*)d_in[17];
    const float* rel_W  = (const float*)d_in[18];

    const int n = in_sizes[0] / 32;
    const int E0 = in_sizes[4] / 2, E1 = in_sizes[5] / 2, E2 = in_sizes[6] / 2, E3 = in_sizes[7] / 2;

    float* out = (float*)d_out;

    // ---- workspace carve ----
    char* base = (char*)d_ws;
    size_t off = 0;
    auto carve = [&](size_t bytes) { char* p = base + off; off += (bytes + 15) & ~(size_t)15; return p; };
    unsigned short* hb_a  = (unsigned short*)carve((size_t)n * H * 2);
    unsigned short* hb_b  = (unsigned short*)carve((size_t)n * H * 2);
    unsigned short* statb = (unsigned short*)carve((size_t)n * H * 2);
    float* XL    = (float*)carve((size_t)n * 16 * 4);
    float* XS    = (float*)carve((size_t)n * 8 * 4);
    float* XI    = (float*)carve((size_t)n * 8 * 4);
    float* recip = (float*)carve((size_t)N_REL * n * 4);
    int* cnt_all    = (int*)carve((size_t)N_REL * n * 4);
    int* rowptr_all = (int*)carve((size_t)N_REL * (n + 1) * 4);
    int* cursor_all = (int*)carve((size_t)N_REL * n * 4);
    int* partial    = (int*)carve((size_t)N_REL * SB * 4);
    int* col0 = (int*)carve((size_t)E0 * 4);
    int* col1 = (int*)carve((size_t)E1 * 4);
    int* col2 = (int*)carve((size_t)E2 * 4);
    int* col3 = (int*)carve((size_t)E3 * 4);

    // ---- CSR build ----
    int4 E4   = { E0, E1, E2, E3 };
    int B0 = (E0 + 255) / 256, B1 = (E1 + 255) / 256, B2 = (E2 + 255) / 256, B3 = (E3 + 255) / 256;
    int4 boff = { 0, B0, B0 + B1, B0 + B1 + B2 };
    int Btot = B0 + B1 + B2 + B3;

    hipMemsetAsync(cnt_all, 0, (size_t)N_REL * n * sizeof(int), stream);
    k_count_all<<<Btot, 256, 0, stream>>>(e_sp, e_fl, e_fs, e_in, E4, boff, cnt_all, n);
    k_scan1<<<N_REL * SB, 256, 0, stream>>>(cnt_all, n, partial);
    k_scan2<<<1, 256, 0, stream>>>(partial, rowptr_all, n, E4);
    k_scan3<<<N_REL * SB, 256, 0, stream>>>(cnt_all, partial, rowptr_all, cursor_all, recip, n);
    k_fill_all<<<Btot, 256, 0, stream>>>(e_sp, e_fl, e_fs, e_in, E4, boff, cursor_all,
                                         col0, col1, col2, col3, n);

    const float* r0 = recip;
    const float* r1 = recip + (size_t)n;
    const float* r2 = recip + 2 * (size_t)n;
    const float* r3 = recip + 3 * (size_t)n;

    // ---- x_int encoder (MFMA) ----
    k_encmfma<<<(n + 63) / 64, 256, 0, stream>>>(x_int, W_int, b_int, hb_a, n);

    // ---- static relations on RAW x, fused small GEMM -> stat (bf16) ----
    int BL = (n + 15) / 16, BS = (n + 31) / 32, BI = (n + 31) / 32;
    k_aggx_all<<<BL + BS + BI, 256, 0, stream>>>(x_lane, x_sens, x_inj, rowptr_all,
                                                 col1, col2, col3, recip, XL, XS, XI, n, BL, BS);
    k_stat<<<(n + 7) / 8, 256, 0, stream>>>(XL, XS, XI, W_lane, W_sens, W_inj,
                                            b_lane, b_sens, b_inj, r1, r2, r3, statb, n);

    // ---- 3 fused layers ----
    const int layer_grid = (n + 63) / 64;
    unsigned short* cur = hb_a;
    unsigned short* nxt = hb_b;
    for (int l = 0; l < 3; ++l) {
        const float* Ws = self_W + (size_t)l * H * H;
        const float* Wr = rel_W  + (size_t)l * H * H;
        const float* bb = self_b + (size_t)l * H;
        if (l == 2)
            k_flayer<1><<<layer_grid, 256, 0, stream>>>(cur, rowptr_all, col0, r0, statb,
                                                        Ws, Wr, bb, nullptr, out, n);
        else
            k_flayer<0><<<layer_grid, 256, 0, stream>>>(cur, rowptr_all, col0, r0, statb,
                                                        Ws, Wr, bb, nxt, nullptr, n);
        unsigned short* t = cur; cur = nxt; nxt = t;
    }
}

// Round 6
// 442.384 us; speedup vs baseline: 1.2486x; 1.2486x over previous
//
#include <hip/hip_runtime.h>
#include <hip/hip_bf16.h>
#include <math.h>

#define H 128
#define N_REL 4
#define SB 64   // scan blocks per relation

typedef float f32x4 __attribute__((ext_vector_type(4)));
typedef __bf16 bf16x8 __attribute__((ext_vector_type(8)));

__device__ __forceinline__ unsigned short f2bf(float f) {
    return __builtin_bit_cast(unsigned short, (__bf16)f);
}
__device__ __forceinline__ unsigned pack2(float lo, float hi) {
    return (unsigned)f2bf(lo) | ((unsigned)f2bf(hi) << 16);
}
__device__ __forceinline__ void acc2(unsigned u, float& a, float& b) {
    union { unsigned u; float f; } x, y;
    x.u = u << 16; y.u = u & 0xffff0000u;
    a += x.f; b += y.f;
}
__device__ __forceinline__ float bflo(unsigned u) {
    union { unsigned u; float f; } x; x.u = u << 16; return x.f;
}
__device__ __forceinline__ float bfhi(unsigned u) {
    union { unsigned u; float f; } x; x.u = u & 0xffff0000u; return x.f;
}

// ---------------- CSR build: counts (all relations, one launch) ----------------
__global__ __launch_bounds__(256) void k_count_all(
    const int* __restrict__ s0, const int* __restrict__ s1,
    const int* __restrict__ s2, const int* __restrict__ s3,
    int4 E, int4 boff, int* __restrict__ cnt_all, int n)
{
    int b = blockIdx.x;
    const int* src; int Er, rel;
    if (b < boff.y)      { rel = 0; src = s0; Er = E.x; }
    else if (b < boff.z) { rel = 1; src = s1; Er = E.y; b -= boff.y; }
    else if (b < boff.w) { rel = 2; src = s2; Er = E.z; b -= boff.z; }
    else                 { rel = 3; src = s3; Er = E.w; b -= boff.w; }
    int e = b * 256 + threadIdx.x;
    if (e < Er) atomicAdd(&cnt_all[(size_t)rel * n + src[Er + e]], 1);
}

__global__ __launch_bounds__(256) void k_scan1(const int* __restrict__ cnt_all, int n,
                                               int* __restrict__ partial)
{
    int rel = blockIdx.x >> 6, blk = blockIdx.x & (SB - 1);
    int chunk = (n + SB - 1) / SB;
    int lo = blk * chunk, hi = min(lo + chunk, n);
    const int* cnt = cnt_all + (size_t)rel * n;
    int s = 0;
    for (int i = lo + threadIdx.x; i < hi; i += 256) s += cnt[i];
    __shared__ int sh[256];
    sh[threadIdx.x] = s; __syncthreads();
    for (int d = 128; d; d >>= 1) {
        if (threadIdx.x < d) sh[threadIdx.x] += sh[threadIdx.x + d];
        __syncthreads();
    }
    if (threadIdx.x == 0) partial[rel * SB + blk] = sh[0];
}

__global__ __launch_bounds__(256) void k_scan2(int* __restrict__ partial,
                                               int* __restrict__ rowptr_all, int n, int4 Etot)
{
    int rel = threadIdx.x >> 6, lane = threadIdx.x & 63;
    int v = partial[rel * SB + lane];
    int inc = v;
    for (int d = 1; d < 64; d <<= 1) {
        int t = __shfl_up(inc, d);
        if (lane >= d) inc += t;
    }
    partial[rel * SB + lane] = inc - v;
    if (lane == 0) {
        int E = (rel == 0) ? Etot.x : (rel == 1) ? Etot.y : (rel == 2) ? Etot.z : Etot.w;
        rowptr_all[(size_t)rel * (n + 1) + n] = E;
    }
}

// recip = (c>0) ? 1/c : 0   (0 doubles as "has edges" mask)
__global__ __launch_bounds__(256) void k_scan3(const int* __restrict__ cnt_all,
                                               const int* __restrict__ partial,
                                               int* __restrict__ rowptr_all,
                                               int* __restrict__ cursor_all,
                                               float* __restrict__ recip_all, int n)
{
    int rel = blockIdx.x >> 6, blk = blockIdx.x & (SB - 1);
    int chunk = (n + SB - 1) / SB;
    int lo = blk * chunk, hi = min(lo + chunk, n);
    const int* cnt = cnt_all + (size_t)rel * n;
    int per = (chunk + 255) >> 8;
    int tlo = min(lo + threadIdx.x * per, hi);
    int thi = min(tlo + per, hi);
    int s = 0;
    for (int i = tlo; i < thi; ++i) s += cnt[i];
    __shared__ int sh[256];
    sh[threadIdx.x] = s; __syncthreads();
    for (int d = 1; d < 256; d <<= 1) {
        int t = (threadIdx.x >= d) ? sh[threadIdx.x - d] : 0;
        __syncthreads();
        sh[threadIdx.x] += t;
        __syncthreads();
    }
    int run = partial[rel * SB + blk] + sh[threadIdx.x] - s;
    int* rowptr = rowptr_all + (size_t)rel * (n + 1);
    int* cursor = cursor_all + (size_t)rel * n;
    float* recip = recip_all + (size_t)rel * n;
    for (int i = tlo; i < thi; ++i) {
        int c = cnt[i];
        rowptr[i] = run;
        cursor[i] = run;
        recip[i] = (c > 0) ? 1.0f / (float)c : 0.0f;
        run += c;
    }
}

__global__ __launch_bounds__(256) void k_fill_all(
    const int* __restrict__ s0, const int* __restrict__ s1,
    const int* __restrict__ s2, const int* __restrict__ s3,
    int4 E, int4 boff, int* __restrict__ cursor_all,
    int* __restrict__ c0, int* __restrict__ c1,
    int* __restrict__ c2, int* __restrict__ c3, int n)
{
    int b = blockIdx.x;
    const int* src; int Er, rel; int* colp;
    if (b < boff.y)      { rel = 0; src = s0; Er = E.x; colp = c0; }
    else if (b < boff.z) { rel = 1; src = s1; Er = E.y; colp = c1; b -= boff.y; }
    else if (b < boff.w) { rel = 2; src = s2; Er = E.z; colp = c2; b -= boff.z; }
    else                 { rel = 3; src = s3; Er = E.w; colp = c3; b -= boff.w; }
    int e = b * 256 + threadIdx.x;
    if (e >= Er) return;
    int t = src[Er + e];
    int slot = atomicAdd(&cursor_all[(size_t)rel * n + t], 1);
    colp[slot] = src[e];
}

// ---------------- MFMA encoder for x_int (K=32, one MFMA step) ----------------
__global__ __launch_bounds__(256) void k_encmfma(const float* __restrict__ x,
                                                 const float* __restrict__ W,
                                                 const float* __restrict__ b,
                                                 unsigned short* __restrict__ h, int n)
{
    __shared__ __align__(16) char WB[128 * 80];
    int tid = threadIdx.x;
    {
        int c = tid & 127, khalf = tid >> 7;
        for (int kk = 0; kk < 16; ++kk) {
            int k = khalf * 16 + kk;
            *(unsigned short*)(WB + c * 80 + k * 2) = f2bf(W[(size_t)k * H + c]);
        }
    }
    int lane = tid & 63, wv = tid >> 6;
    int r16 = lane & 15, kgrp = lane >> 4;
    int rowbase = blockIdx.x * 64 + wv * 16;
    int arow = rowbase + r16; if (arow >= n) arow = n - 1;
    const float* xr = x + (size_t)arow * 32 + kgrp * 8;
    float4 xa = *(const float4*)xr, xb = *(const float4*)(xr + 4);
    bf16x8 af;
    af[0] = (__bf16)xa.x; af[1] = (__bf16)xa.y; af[2] = (__bf16)xa.z; af[3] = (__bf16)xa.w;
    af[4] = (__bf16)xb.x; af[5] = (__bf16)xb.y; af[6] = (__bf16)xb.z; af[7] = (__bf16)xb.w;
    __syncthreads();
#pragma unroll
    for (int ct = 0; ct < 8; ++ct) {
        int c = ct * 16 + r16;
        bf16x8 bf = *(const bf16x8*)(WB + c * 80 + kgrp * 16);
        f32x4 acc = { 0.f, 0.f, 0.f, 0.f };
        acc = __builtin_amdgcn_mfma_f32_16x16x32_bf16(af, bf, acc, 0, 0, 0);
        float bb = b[c];
#pragma unroll
        for (int i = 0; i < 4; ++i) {
            int grow = rowbase + kgrp * 4 + i;
            if (grow < n) h[(size_t)grow * H + c] = f2bf(acc[i] + bb);
        }
    }
}

// ---------------- static relations: gather-mean of RAW x (one launch) ----------------
template<int D>
__device__ __forceinline__ void aggx_body(const float* __restrict__ x,
                                          const int* __restrict__ rowptr,
                                          const int* __restrict__ col,
                                          const float* __restrict__ recip,
                                          float* __restrict__ out, int n, int b)
{
    const int rpb = 256 / D;
    int row = b * rpb + (int)(threadIdx.x / D);
    if (row >= n) return;
    int d = threadIdx.x & (D - 1);
    int beg = rowptr[row], end = rowptr[row + 1];
    float s0 = 0.f, s1 = 0.f;
    int e = beg;
    for (; e + 2 <= end; e += 2) {
        s0 += x[(size_t)col[e] * D + d];
        s1 += x[(size_t)col[e + 1] * D + d];
    }
    if (e < end) s0 += x[(size_t)col[e] * D + d];
    out[(size_t)row * D + d] = (s0 + s1) * recip[row];
}

__global__ __launch_bounds__(256) void k_aggx_all(
    const float* __restrict__ xL, const float* __restrict__ xS, const float* __restrict__ xI,
    const int* __restrict__ rowptr_all,
    const int* __restrict__ cL, const int* __restrict__ cS, const int* __restrict__ cI,
    const float* __restrict__ recip_all,
    float* __restrict__ XL, float* __restrict__ XS, float* __restrict__ XI,
    int n, int BL, int BS)
{
    int b = blockIdx.x;
    if (b < BL)
        aggx_body<16>(xL, rowptr_all + (size_t)(n + 1), cL, recip_all + (size_t)n, XL, n, b);
    else if (b < BL + BS)
        aggx_body<8>(xS, rowptr_all + 2 * (size_t)(n + 1), cS, recip_all + 2 * (size_t)n, XS, n, b - BL);
    else
        aggx_body<8>(xI, rowptr_all + 3 * (size_t)(n + 1), cI, recip_all + 3 * (size_t)n, XI, n, b - BL - BS);
}

// ---------------- stat(bf16) = XL@WL + XS@WS + XI@WI + masked biases ----------------
__global__ __launch_bounds__(256) void k_stat(
    const float* __restrict__ XL, const float* __restrict__ XS, const float* __restrict__ XI,
    const float* __restrict__ WL, const float* __restrict__ WSn, const float* __restrict__ WI,
    const float* __restrict__ bL, const float* __restrict__ bS, const float* __restrict__ bI,
    const float* __restrict__ rL, const float* __restrict__ rS, const float* __restrict__ rI,
    unsigned short* __restrict__ statb, int n)
{
    __shared__ float Wc[32][128];
    __shared__ float xs[8][32];
    int t = threadIdx.x;
    for (int i = t; i < 16 * 128; i += 256) Wc[i >> 7][i & 127] = WL[i];
    for (int i = t; i < 8 * 128; i += 256)  Wc[16 + (i >> 7)][i & 127] = WSn[i];
    for (int i = t; i < 8 * 128; i += 256)  Wc[24 + (i >> 7)][i & 127] = WI[i];
    {
        int rr = t >> 5, k = t & 31;
        int rrow = blockIdx.x * 8 + rr; if (rrow >= n) rrow = n - 1;
        float v;
        if (k < 16)      v = XL[(size_t)rrow * 16 + k];
        else if (k < 24) v = XS[(size_t)rrow * 8 + (k - 16)];
        else             v = XI[(size_t)rrow * 8 + (k - 24)];
        xs[rr][k] = v;
    }
    __syncthreads();
    int rl = t >> 5, c4 = (t & 31) << 2;
    int row = blockIdx.x * 8 + rl;
    float a0 = 0.f, a1 = 0.f, a2 = 0.f, a3 = 0.f;
#pragma unroll
    for (int k = 0; k < 32; ++k) {
        float xv = xs[rl][k];
        a0 += xv * Wc[k][c4 + 0]; a1 += xv * Wc[k][c4 + 1];
        a2 += xv * Wc[k][c4 + 2]; a3 += xv * Wc[k][c4 + 3];
    }
    if (row < n) {
        float mL = (rL[row] > 0.f) ? 1.f : 0.f;
        float mS = (rS[row] > 0.f) ? 1.f : 0.f;
        float mI = (rI[row] > 0.f) ? 1.f : 0.f;
        uint2 res;
        res.x = pack2(a0 + mL * bL[c4 + 0] + mS * bS[c4 + 0] + mI * bI[c4 + 0],
                      a1 + mL * bL[c4 + 1] + mS * bS[c4 + 1] + mI * bI[c4 + 1]);
        res.y = pack2(a2 + mL * bL[c4 + 2] + mS * bS[c4 + 2] + mI * bI[c4 + 2],
                      a3 + mL * bL[c4 + 3] + mS * bS[c4 + 3] + mI * bI[c4 + 3]);
        *(uint2*)(statb + (size_t)row * H + c4) = res;
    }
}

// ---------------- spatial SpMM: aggb = bf16(mean(hb_nbr) + statb) ----------------
// 16 lanes/row, 16B (8 bf16) per lane, 4-edge unroll
__global__ __launch_bounds__(256) void k_spmm(const unsigned short* __restrict__ hsrc,
                                              const int* __restrict__ rowptr,
                                              const int* __restrict__ col,
                                              const float* __restrict__ recip,
                                              const unsigned short* __restrict__ statb,
                                              unsigned short* __restrict__ aggout, int n)
{
    int row = blockIdx.x * 16 + (threadIdx.x >> 4);
    if (row >= n) return;
    int q = (threadIdx.x & 15) << 3;   // 8 bf16 per lane
    int beg = rowptr[row], end = rowptr[row + 1];

    float a0 = 0.f, a1 = 0.f, a2 = 0.f, a3 = 0.f, a4 = 0.f, a5 = 0.f, a6 = 0.f, a7 = 0.f;
    int e = beg;
    for (; e + 4 <= end; e += 4) {
        int s0 = col[e], s1 = col[e + 1], s2 = col[e + 2], s3 = col[e + 3];
        uint4 v0 = *(const uint4*)(hsrc + (size_t)s0 * H + q);
        uint4 v1 = *(const uint4*)(hsrc + (size_t)s1 * H + q);
        uint4 v2 = *(const uint4*)(hsrc + (size_t)s2 * H + q);
        uint4 v3 = *(const uint4*)(hsrc + (size_t)s3 * H + q);
        acc2(v0.x, a0, a1); acc2(v0.y, a2, a3); acc2(v0.z, a4, a5); acc2(v0.w, a6, a7);
        acc2(v1.x, a0, a1); acc2(v1.y, a2, a3); acc2(v1.z, a4, a5); acc2(v1.w, a6, a7);
        acc2(v2.x, a0, a1); acc2(v2.y, a2, a3); acc2(v2.z, a4, a5); acc2(v2.w, a6, a7);
        acc2(v3.x, a0, a1); acc2(v3.y, a2, a3); acc2(v3.z, a4, a5); acc2(v3.w, a6, a7);
    }
    for (; e < end; ++e) {
        uint4 v0 = *(const uint4*)(hsrc + (size_t)col[e] * H + q);
        acc2(v0.x, a0, a1); acc2(v0.y, a2, a3); acc2(v0.z, a4, a5); acc2(v0.w, a6, a7);
    }

    float r = recip[row];
    size_t o = (size_t)row * H + q;
    uint4 sv = *(const uint4*)(statb + o);
    uint4 w;
    w.x = pack2(a0 * r + bflo(sv.x), a1 * r + bfhi(sv.x));
    w.y = pack2(a2 * r + bflo(sv.y), a3 * r + bfhi(sv.y));
    w.z = pack2(a4 * r + bflo(sv.z), a5 * r + bfhi(sv.z));
    w.w = pack2(a6 * r + bflo(sv.w), a7 * r + bfhi(sv.w));
    *(uint4*)(aggout + o) = w;
}

// ---------------- MFMA layer: elu([h|agg] @ [Wself;Wrel] + b) ----------------
template<int LAST>
__global__ __launch_bounds__(256) void k_layer(const unsigned short* __restrict__ hb,
                                               const unsigned short* __restrict__ aggb,
                                               const float* __restrict__ Ws,
                                               const float* __restrict__ Wr,
                                               const float* __restrict__ bias,
                                               unsigned short* __restrict__ hbout,
                                               float* __restrict__ fout, int n)
{
    __shared__ __align__(16) char BT[128 * 256 * 2];

    int tid = threadIdx.x;
    {
        int c = tid & 127, half = tid >> 7;
        for (int kc = half; kc < 32; kc += 2) {
            int kk0 = kc * 8;
            const float* Wsrc = (kk0 < 128) ? (Ws + (size_t)kk0 * H + c)
                                            : (Wr + (size_t)(kk0 - 128) * H + c);
            bf16x8 pack;
#pragma unroll
            for (int j = 0; j < 8; ++j) pack[j] = (__bf16)Wsrc[(size_t)j * H];
            int woff = c * 512 + ((kc * 16) ^ ((c & 7) << 4));
            *(bf16x8*)(BT + woff) = pack;
        }
    }

    int lane = tid & 63, wv = tid >> 6;
    int r16 = lane & 15, kgrp = lane >> 4;
    int rowbase = blockIdx.x * 64 + wv * 16;
    int arow = rowbase + r16; if (arow >= n) arow = n - 1;

    bf16x8 afrag[8];
#pragma unroll
    for (int ks = 0; ks < 8; ++ks) {
        int k0 = ks * 32 + kgrp * 8;
        const unsigned short* src = (k0 < 128) ? (hb + (size_t)arow * H + k0)
                                               : (aggb + (size_t)arow * H + (k0 - 128));
        afrag[ks] = *(const bf16x8*)src;
    }
    __syncthreads();

#pragma unroll
    for (int ct = 0; ct < 8; ++ct) {
        int c = ct * 16 + r16;
        f32x4 acc = { 0.f, 0.f, 0.f, 0.f };
#pragma unroll
        for (int ks = 0; ks < 8; ++ks) {
            int kbyte = ks * 64 + kgrp * 16;
            int off = c * 512 + (kbyte ^ ((c & 7) << 4));
            bf16x8 bfrag = *(const bf16x8*)(BT + off);
            acc = __builtin_amdgcn_mfma_f32_16x16x32_bf16(afrag[ks], bfrag, acc, 0, 0, 0);
        }
        float bb = bias[c];
#pragma unroll
        for (int i = 0; i < 4; ++i) {
            int grow = rowbase + kgrp * 4 + i;
            if (grow < n) {
                float v = acc[i] + bb;
                v = (v > 0.f) ? v : (expf(v) - 1.f);
                if (LAST) fout[(size_t)grow * H + c] = v;
                else      hbout[(size_t)grow * H + c] = f2bf(v);
            }
        }
    }
}

extern "C" void kernel_launch(void* const* d_in, const int* in_sizes, int n_in,
                              void* d_out, int out_size, void* d_ws, size_t ws_size,
                              hipStream_t stream)
{
    const float* x_int  = (const float*)d_in[0];
    const float* x_lane = (const float*)d_in[1];
    const float* x_sens = (const float*)d_in[2];
    const float* x_inj  = (const float*)d_in[3];
    const int*   e_sp   = (const int*)d_in[4];
    const int*   e_fl   = (const int*)d_in[5];
    const int*   e_fs   = (const int*)d_in[6];
    const int*   e_in   = (const int*)d_in[7];
    const float* W_int  = (const float*)d_in[8];
    const float* b_int  = (const float*)d_in[9];
    const float* W_lane = (const float*)d_in[10];
    const float* b_lane = (const float*)d_in[11];
    const float* W_sens = (const float*)d_in[12];
    const float* b_sens = (const float*)d_in[13];
    const float* W_inj  = (const float*)d_in[14];
    const float* b_inj  = (const float*)d_in[15];
    const float* self_W = (const float*)d_in[16];
    const float* self_b = (const float*)d_in[17];
    const float* rel_W  = (const float*)d_in[18];

    const int n = in_sizes[0] / 32;
    const int E0 = in_sizes[4] / 2, E1 = in_sizes[5] / 2, E2 = in_sizes[6] / 2, E3 = in_sizes[7] / 2;

    float* out = (float*)d_out;

    // ---- workspace carve ----
    char* base = (char*)d_ws;
    size_t off = 0;
    auto carve = [&](size_t bytes) { char* p = base + off; off += (bytes + 15) & ~(size_t)15; return p; };
    unsigned short* hb_a  = (unsigned short*)carve((size_t)n * H * 2);
    unsigned short* hb_b  = (unsigned short*)carve((size_t)n * H * 2);
    unsigned short* aggb  = (unsigned short*)carve((size_t)n * H * 2);
    unsigned short* statb = (unsigned short*)carve((size_t)n * H * 2);
    float* XL    = (float*)carve((size_t)n * 16 * 4);
    float* XS    = (float*)carve((size_t)n * 8 * 4);
    float* XI    = (float*)carve((size_t)n * 8 * 4);
    float* recip = (float*)carve((size_t)N_REL * n * 4);
    int* cnt_all    = (int*)carve((size_t)N_REL * n * 4);
    int* rowptr_all = (int*)carve((size_t)N_REL * (n + 1) * 4);
    int* cursor_all = (int*)carve((size_t)N_REL * n * 4);
    int* partial    = (int*)carve((size_t)N_REL * SB * 4);
    int* col0 = (int*)carve((size_t)E0 * 4);
    int* col1 = (int*)carve((size_t)E1 * 4);
    int* col2 = (int*)carve((size_t)E2 * 4);
    int* col3 = (int*)carve((size_t)E3 * 4);

    // ---- CSR build ----
    int4 E4   = { E0, E1, E2, E3 };
    int B0 = (E0 + 255) / 256, B1 = (E1 + 255) / 256, B2 = (E2 + 255) / 256, B3 = (E3 + 255) / 256;
    int4 boff = { 0, B0, B0 + B1, B0 + B1 + B2 };
    int Btot = B0 + B1 + B2 + B3;

    hipMemsetAsync(cnt_all, 0, (size_t)N_REL * n * sizeof(int), stream);
    k_count_all<<<Btot, 256, 0, stream>>>(e_sp, e_fl, e_fs, e_in, E4, boff, cnt_all, n);
    k_scan1<<<N_REL * SB, 256, 0, stream>>>(cnt_all, n, partial);
    k_scan2<<<1, 256, 0, stream>>>(partial, rowptr_all, n, E4);
    k_scan3<<<N_REL * SB, 256, 0, stream>>>(cnt_all, partial, rowptr_all, cursor_all, recip, n);
    k_fill_all<<<Btot, 256, 0, stream>>>(e_sp, e_fl, e_fs, e_in, E4, boff, cursor_all,
                                         col0, col1, col2, col3, n);

    const float* r0 = recip;
    const float* r1 = recip + (size_t)n;
    const float* r2 = recip + 2 * (size_t)n;
    const float* r3 = recip + 3 * (size_t)n;

    // ---- x_int encoder (MFMA) ----
    k_encmfma<<<(n + 63) / 64, 256, 0, stream>>>(x_int, W_int, b_int, hb_a, n);

    // ---- static relations on RAW x, fused small GEMM -> stat (bf16) ----
    int BL = (n + 15) / 16, BS = (n + 31) / 32, BI = (n + 31) / 32;
    k_aggx_all<<<BL + BS + BI, 256, 0, stream>>>(x_lane, x_sens, x_inj, rowptr_all,
                                                 col1, col2, col3, recip, XL, XS, XI, n, BL, BS);
    k_stat<<<(n + 7) / 8, 256, 0, stream>>>(XL, XS, XI, W_lane, W_sens, W_inj,
                                            b_lane, b_sens, b_inj, r1, r2, r3, statb, n);

    // ---- 3 layers ----
    const int spmm_grid = (n + 15) / 16;
    const int layer_grid = (n + 63) / 64;
    unsigned short* cur = hb_a;
    unsigned short* nxt = hb_b;
    for (int l = 0; l < 3; ++l) {
        k_spmm<<<spmm_grid, 256, 0, stream>>>(cur, rowptr_all, col0, r0, statb, aggb, n);
        const float* Ws = self_W + (size_t)l * H * H;
        const float* Wr = rel_W  + (size_t)l * H * H;
        const float* bb = self_b + (size_t)l * H;
        if (l == 2)
            k_layer<1><<<layer_grid, 256, 0, stream>>>(cur, aggb, Ws, Wr, bb, nullptr, out, n);
        else
            k_layer<0><<<layer_grid, 256, 0, stream>>>(cur, aggb, Ws, Wr, bb, nxt, nullptr, n);
        unsigned short* t = cur; cur = nxt; nxt = t;
    }
}

// Round 7
// 386.659 us; speedup vs baseline: 1.4285x; 1.1441x over previous
//
#include <hip/hip_runtime.h>
#include <hip/hip_bf16.h>
#include <math.h>

#define H 128
#define N_REL 4
#define SB 64   // scan blocks (spatial relation)

typedef float f32x4 __attribute__((ext_vector_type(4)));
typedef __bf16 bf16x8 __attribute__((ext_vector_type(8)));

__device__ __forceinline__ unsigned short f2bf(float f) {
    return __builtin_bit_cast(unsigned short, (__bf16)f);
}
__device__ __forceinline__ unsigned pack2(float lo, float hi) {
    return (unsigned)f2bf(lo) | ((unsigned)f2bf(hi) << 16);
}
__device__ __forceinline__ void acc2(unsigned u, float& a, float& b) {
    union { unsigned u; float f; } x, y;
    x.u = u << 16; y.u = u & 0xffff0000u;
    a += x.f; b += y.f;
}
__device__ __forceinline__ float bflo(unsigned u) {
    union { unsigned u; float f; } x; x.u = u << 16; return x.f;
}
__device__ __forceinline__ float bfhi(unsigned u) {
    union { unsigned u; float f; } x; x.u = u & 0xffff0000u; return x.f;
}

// ---------------- counts (all 4 relations, one launch) ----------------
__global__ __launch_bounds__(256) void k_count_all(
    const int* __restrict__ s0, const int* __restrict__ s1,
    const int* __restrict__ s2, const int* __restrict__ s3,
    int4 E, int4 boff, int* __restrict__ cnt_all, int n)
{
    int b = blockIdx.x;
    const int* src; int Er, rel;
    if (b < boff.y)      { rel = 0; src = s0; Er = E.x; }
    else if (b < boff.z) { rel = 1; src = s1; Er = E.y; b -= boff.y; }
    else if (b < boff.w) { rel = 2; src = s2; Er = E.z; b -= boff.z; }
    else                 { rel = 3; src = s3; Er = E.w; b -= boff.w; }
    int e = b * 256 + threadIdx.x;
    if (e < Er) atomicAdd(&cnt_all[(size_t)rel * n + src[Er + e]], 1);
}

// ---------------- 3-phase scan, SPATIAL relation only ----------------
__global__ __launch_bounds__(256) void k_scan1(const int* __restrict__ cnt, int n,
                                               int* __restrict__ partial)
{
    int blk = blockIdx.x;
    int chunk = (n + SB - 1) / SB;
    int lo = blk * chunk, hi = min(lo + chunk, n);
    int s = 0;
    for (int i = lo + threadIdx.x; i < hi; i += 256) s += cnt[i];
    __shared__ int sh[256];
    sh[threadIdx.x] = s; __syncthreads();
    for (int d = 128; d; d >>= 1) {
        if (threadIdx.x < d) sh[threadIdx.x] += sh[threadIdx.x + d];
        __syncthreads();
    }
    if (threadIdx.x == 0) partial[blk] = sh[0];
}

__global__ __launch_bounds__(64) void k_scan2(int* __restrict__ partial,
                                              int* __restrict__ rowptr, int n, int E0)
{
    int lane = threadIdx.x;
    int v = partial[lane];
    int inc = v;
    for (int d = 1; d < 64; d <<= 1) {
        int t = __shfl_up(inc, d);
        if (lane >= d) inc += t;
    }
    partial[lane] = inc - v;
    if (lane == 0) rowptr[n] = E0;
}

__global__ __launch_bounds__(256) void k_scan3(const int* __restrict__ cnt,
                                               const int* __restrict__ partial,
                                               int* __restrict__ rowptr,
                                               int* __restrict__ cursor,
                                               float* __restrict__ recip, int n)
{
    int blk = blockIdx.x;
    int chunk = (n + SB - 1) / SB;
    int lo = blk * chunk, hi = min(lo + chunk, n);
    int per = (chunk + 255) >> 8;
    int tlo = min(lo + threadIdx.x * per, hi);
    int thi = min(tlo + per, hi);
    int s = 0;
    for (int i = tlo; i < thi; ++i) s += cnt[i];
    __shared__ int sh[256];
    sh[threadIdx.x] = s; __syncthreads();
    for (int d = 1; d < 256; d <<= 1) {
        int t = (threadIdx.x >= d) ? sh[threadIdx.x - d] : 0;
        __syncthreads();
        sh[threadIdx.x] += t;
        __syncthreads();
    }
    int run = partial[blk] + sh[threadIdx.x] - s;
    for (int i = tlo; i < thi; ++i) {
        int c = cnt[i];
        rowptr[i] = run;
        cursor[i] = run;
        recip[i] = (c > 0) ? 1.0f / (float)c : 0.0f;
        run += c;
    }
}

// recip for static relations (1..3), straight from counts
__global__ __launch_bounds__(256) void k_recip123(const int* __restrict__ cnt_all,
                                                  float* __restrict__ recip_all, int n)
{
    int i = blockIdx.x * 256 + threadIdx.x;
    if (i >= 3 * n) return;
    int c = cnt_all[n + i];
    recip_all[n + i] = (c > 0) ? 1.0f / (float)c : 0.0f;
}

// fill: SPATIAL only
__global__ __launch_bounds__(256) void k_fill(const int* __restrict__ s0, int E0,
                                              int* __restrict__ cursor, int* __restrict__ col)
{
    int e = blockIdx.x * 256 + threadIdx.x;
    if (e >= E0) return;
    int t = s0[E0 + e];
    int slot = atomicAdd(&cursor[t], 1);
    col[slot] = s0[e];
}

// ---------------- static relations: push-scatter of raw x into L3-resident ACC ----------------
__global__ __launch_bounds__(256) void k_scatx_all(
    const int* __restrict__ s1, const int* __restrict__ s2, const int* __restrict__ s3,
    const float* __restrict__ xL, const float* __restrict__ xS, const float* __restrict__ xI,
    int E1, int E2, int E3, int b1, int b2,
    float* __restrict__ XL, float* __restrict__ XS, float* __restrict__ XI)
{
    int b = blockIdx.x;
    if (b < b1) {
        int e = b * 16 + (threadIdx.x >> 4);
        if (e >= E1) return;
        int d = threadIdx.x & 15;
        int src = s1[e], tgt = s1[E1 + e];
        unsafeAtomicAdd(&XL[(size_t)tgt * 16 + d], xL[(size_t)src * 16 + d]);
    } else if (b < b2) {
        b -= b1;
        int e = b * 32 + (threadIdx.x >> 3);
        if (e >= E2) return;
        int d = threadIdx.x & 7;
        int src = s2[e], tgt = s2[E2 + e];
        unsafeAtomicAdd(&XS[(size_t)tgt * 8 + d], xS[(size_t)src * 8 + d]);
    } else {
        b -= b2;
        int e = b * 32 + (threadIdx.x >> 3);
        if (e >= E3) return;
        int d = threadIdx.x & 7;
        int src = s3[e], tgt = s3[E3 + e];
        unsafeAtomicAdd(&XI[(size_t)tgt * 8 + d], xI[(size_t)src * 8 + d]);
    }
}

// ---------------- MFMA encoder for x_int (K=32, one MFMA step) ----------------
__global__ __launch_bounds__(256) void k_encmfma(const float* __restrict__ x,
                                                 const float* __restrict__ W,
                                                 const float* __restrict__ b,
                                                 unsigned short* __restrict__ h, int n)
{
    __shared__ __align__(16) char WB[128 * 80];
    int tid = threadIdx.x;
    {
        int c = tid & 127, khalf = tid >> 7;
        for (int kk = 0; kk < 16; ++kk) {
            int k = khalf * 16 + kk;
            *(unsigned short*)(WB + c * 80 + k * 2) = f2bf(W[(size_t)k * H + c]);
        }
    }
    int lane = tid & 63, wv = tid >> 6;
    int r16 = lane & 15, kgrp = lane >> 4;
    int rowbase = blockIdx.x * 64 + wv * 16;
    int arow = rowbase + r16; if (arow >= n) arow = n - 1;
    const float* xr = x + (size_t)arow * 32 + kgrp * 8;
    float4 xa = *(const float4*)xr, xb = *(const float4*)(xr + 4);
    bf16x8 af;
    af[0] = (__bf16)xa.x; af[1] = (__bf16)xa.y; af[2] = (__bf16)xa.z; af[3] = (__bf16)xa.w;
    af[4] = (__bf16)xb.x; af[5] = (__bf16)xb.y; af[6] = (__bf16)xb.z; af[7] = (__bf16)xb.w;
    __syncthreads();
#pragma unroll
    for (int ct = 0; ct < 8; ++ct) {
        int c = ct * 16 + r16;
        bf16x8 bf = *(const bf16x8*)(WB + c * 80 + kgrp * 16);
        f32x4 acc = { 0.f, 0.f, 0.f, 0.f };
        acc = __builtin_amdgcn_mfma_f32_16x16x32_bf16(af, bf, acc, 0, 0, 0);
        float bb = b[c];
#pragma unroll
        for (int i = 0; i < 4; ++i) {
            int grow = rowbase + kgrp * 4 + i;
            if (grow < n) h[(size_t)grow * H + c] = f2bf(acc[i] + bb);
        }
    }
}

// ---------------- stat(bf16) = (XL*rL)@WL + (XS*rS)@WS + (XI*rI)@WI + masked biases ----------------
__global__ __launch_bounds__(256) void k_stat(
    const float* __restrict__ XL, const float* __restrict__ XS, const float* __restrict__ XI,
    const float* __restrict__ WL, const float* __restrict__ WSn, const float* __restrict__ WI,
    const float* __restrict__ bL, const float* __restrict__ bS, const float* __restrict__ bI,
    const float* __restrict__ rL, const float* __restrict__ rS, const float* __restrict__ rI,
    unsigned short* __restrict__ statb, int n)
{
    __shared__ float Wc[32][128];
    __shared__ float xs[8][32];
    int t = threadIdx.x;
    for (int i = t; i < 16 * 128; i += 256) Wc[i >> 7][i & 127] = WL[i];
    for (int i = t; i < 8 * 128; i += 256)  Wc[16 + (i >> 7)][i & 127] = WSn[i];
    for (int i = t; i < 8 * 128; i += 256)  Wc[24 + (i >> 7)][i & 127] = WI[i];
    {
        int rr = t >> 5, k = t & 31;
        int rrow = blockIdx.x * 8 + rr; if (rrow >= n) rrow = n - 1;
        float v;
        if (k < 16)      v = XL[(size_t)rrow * 16 + k] * rL[rrow];
        else if (k < 24) v = XS[(size_t)rrow * 8 + (k - 16)] * rS[rrow];
        else             v = XI[(size_t)rrow * 8 + (k - 24)] * rI[rrow];
        xs[rr][k] = v;
    }
    __syncthreads();
    int rl = t >> 5, c4 = (t & 31) << 2;
    int row = blockIdx.x * 8 + rl;
    float a0 = 0.f, a1 = 0.f, a2 = 0.f, a3 = 0.f;
#pragma unroll
    for (int k = 0; k < 32; ++k) {
        float xv = xs[rl][k];
        a0 += xv * Wc[k][c4 + 0]; a1 += xv * Wc[k][c4 + 1];
        a2 += xv * Wc[k][c4 + 2]; a3 += xv * Wc[k][c4 + 3];
    }
    if (row < n) {
        float mL = (rL[row] > 0.f) ? 1.f : 0.f;
        float mS = (rS[row] > 0.f) ? 1.f : 0.f;
        float mI = (rI[row] > 0.f) ? 1.f : 0.f;
        uint2 res;
        res.x = pack2(a0 + mL * bL[c4 + 0] + mS * bS[c4 + 0] + mI * bI[c4 + 0],
                      a1 + mL * bL[c4 + 1] + mS * bS[c4 + 1] + mI * bI[c4 + 1]);
        res.y = pack2(a2 + mL * bL[c4 + 2] + mS * bS[c4 + 2] + mI * bI[c4 + 2],
                      a3 + mL * bL[c4 + 3] + mS * bS[c4 + 3] + mI * bI[c4 + 3]);
        *(uint2*)(statb + (size_t)row * H + c4) = res;
    }
}

// ---------------- spatial SpMM: aggb = bf16(mean(hb_nbr) + statb) ----------------
__global__ __launch_bounds__(256) void k_spmm(const unsigned short* __restrict__ hsrc,
                                              const int* __restrict__ rowptr,
                                              const int* __restrict__ col,
                                              const float* __restrict__ recip,
                                              const unsigned short* __restrict__ statb,
                                              unsigned short* __restrict__ aggout, int n)
{
    int row = blockIdx.x * 16 + (threadIdx.x >> 4);
    if (row >= n) return;
    int q = (threadIdx.x & 15) << 3;   // 8 bf16 per lane
    int beg = rowptr[row], end = rowptr[row + 1];

    float a0 = 0.f, a1 = 0.f, a2 = 0.f, a3 = 0.f, a4 = 0.f, a5 = 0.f, a6 = 0.f, a7 = 0.f;
    int e = beg;
    for (; e + 4 <= end; e += 4) {
        int s0 = col[e], s1 = col[e + 1], s2 = col[e + 2], s3 = col[e + 3];
        uint4 v0 = *(const uint4*)(hsrc + (size_t)s0 * H + q);
        uint4 v1 = *(const uint4*)(hsrc + (size_t)s1 * H + q);
        uint4 v2 = *(const uint4*)(hsrc + (size_t)s2 * H + q);
        uint4 v3 = *(const uint4*)(hsrc + (size_t)s3 * H + q);
        acc2(v0.x, a0, a1); acc2(v0.y, a2, a3); acc2(v0.z, a4, a5); acc2(v0.w, a6, a7);
        acc2(v1.x, a0, a1); acc2(v1.y, a2, a3); acc2(v1.z, a4, a5); acc2(v1.w, a6, a7);
        acc2(v2.x, a0, a1); acc2(v2.y, a2, a3); acc2(v2.z, a4, a5); acc2(v2.w, a6, a7);
        acc2(v3.x, a0, a1); acc2(v3.y, a2, a3); acc2(v3.z, a4, a5); acc2(v3.w, a6, a7);
    }
    for (; e < end; ++e) {
        uint4 v0 = *(const uint4*)(hsrc + (size_t)col[e] * H + q);
        acc2(v0.x, a0, a1); acc2(v0.y, a2, a3); acc2(v0.z, a4, a5); acc2(v0.w, a6, a7);
    }

    float r = recip[row];
    size_t o = (size_t)row * H + q;
    uint4 sv = *(const uint4*)(statb + o);
    uint4 w;
    w.x = pack2(a0 * r + bflo(sv.x), a1 * r + bfhi(sv.x));
    w.y = pack2(a2 * r + bflo(sv.y), a3 * r + bfhi(sv.y));
    w.z = pack2(a4 * r + bflo(sv.z), a5 * r + bfhi(sv.z));
    w.w = pack2(a6 * r + bflo(sv.w), a7 * r + bfhi(sv.w));
    *(uint4*)(aggout + o) = w;
}

// ---------------- MFMA layer: elu([h|agg] @ [Wself;Wrel] + b) ----------------
template<int LAST>
__global__ __launch_bounds__(256) void k_layer(const unsigned short* __restrict__ hb,
                                               const unsigned short* __restrict__ aggb,
                                               const float* __restrict__ Ws,
                                               const float* __restrict__ Wr,
                                               const float* __restrict__ bias,
                                               unsigned short* __restrict__ hbout,
                                               float* __restrict__ fout, int n)
{
    __shared__ __align__(16) char BT[128 * 256 * 2];

    int tid = threadIdx.x;
    {
        int c = tid & 127, half = tid >> 7;
        for (int kc = half; kc < 32; kc += 2) {
            int kk0 = kc * 8;
            const float* Wsrc = (kk0 < 128) ? (Ws + (size_t)kk0 * H + c)
                                            : (Wr + (size_t)(kk0 - 128) * H + c);
            bf16x8 pack;
#pragma unroll
            for (int j = 0; j < 8; ++j) pack[j] = (__bf16)Wsrc[(size_t)j * H];
            int woff = c * 512 + ((kc * 16) ^ ((c & 7) << 4));
            *(bf16x8*)(BT + woff) = pack;
        }
    }

    int lane = tid & 63, wv = tid >> 6;
    int r16 = lane & 15, kgrp = lane >> 4;
    int rowbase = blockIdx.x * 64 + wv * 16;
    int arow = rowbase + r16; if (arow >= n) arow = n - 1;

    bf16x8 afrag[8];
#pragma unroll
    for (int ks = 0; ks < 8; ++ks) {
        int k0 = ks * 32 + kgrp * 8;
        const unsigned short* src = (k0 < 128) ? (hb + (size_t)arow * H + k0)
                                               : (aggb + (size_t)arow * H + (k0 - 128));
        afrag[ks] = *(const bf16x8*)src;
    }
    __syncthreads();

#pragma unroll
    for (int ct = 0; ct < 8; ++ct) {
        int c = ct * 16 + r16;
        f32x4 acc = { 0.f, 0.f, 0.f, 0.f };
#pragma unroll
        for (int ks = 0; ks < 8; ++ks) {
            int kbyte = ks * 64 + kgrp * 16;
            int off = c * 512 + (kbyte ^ ((c & 7) << 4));
            bf16x8 bfrag = *(const bf16x8*)(BT + off);
            acc = __builtin_amdgcn_mfma_f32_16x16x32_bf16(afrag[ks], bfrag, acc, 0, 0, 0);
        }
        float bb = bias[c];
#pragma unroll
        for (int i = 0; i < 4; ++i) {
            int grow = rowbase + kgrp * 4 + i;
            if (grow < n) {
                float v = acc[i] + bb;
                v = (v > 0.f) ? v : (expf(v) - 1.f);
                if (LAST) fout[(size_t)grow * H + c] = v;
                else      hbout[(size_t)grow * H + c] = f2bf(v);
            }
        }
    }
}

extern "C" void kernel_launch(void* const* d_in, const int* in_sizes, int n_in,
                              void* d_out, int out_size, void* d_ws, size_t ws_size,
                              hipStream_t stream)
{
    const float* x_int  = (const float*)d_in[0];
    const float* x_lane = (const float*)d_in[1];
    const float* x_sens = (const float*)d_in[2];
    const float* x_inj  = (const float*)d_in[3];
    const int*   e_sp   = (const int*)d_in[4];
    const int*   e_fl   = (const int*)d_in[5];
    const int*   e_fs   = (const int*)d_in[6];
    const int*   e_in   = (const int*)d_in[7];
    const float* W_int  = (const float*)d_in[8];
    const float* b_int  = (const float*)d_in[9];
    const float* W_lane = (const float*)d_in[10];
    const float* b_lane = (const float*)d_in[11];
    const float* W_sens = (const float*)d_in[12];
    const float* b_sens = (const float*)d_in[13];
    const float* W_inj  = (const float*)d_in[14];
    const float* b_inj  = (const float*)d_in[15];
    const float* self_W = (const float*)d_in[16];
    const float* self_b = (const float*)d_in[17];
    const float* rel_W  = (const float*)d_in[18];

    const int n = in_sizes[0] / 32;
    const int E0 = in_sizes[4] / 2, E1 = in_sizes[5] / 2, E2 = in_sizes[6] / 2, E3 = in_sizes[7] / 2;

    float* out = (float*)d_out;

    // ---- workspace carve ----
    char* base = (char*)d_ws;
    size_t off = 0;
    auto carve = [&](size_t bytes) { char* p = base + off; off += (bytes + 15) & ~(size_t)15; return p; };
    unsigned short* hb_a  = (unsigned short*)carve((size_t)n * H * 2);
    unsigned short* hb_b  = (unsigned short*)carve((size_t)n * H * 2);
    unsigned short* aggb  = (unsigned short*)carve((size_t)n * H * 2);
    unsigned short* statb = (unsigned short*)carve((size_t)n * H * 2);
    float* ACC   = (float*)carve((size_t)n * 32 * 4);   // XL(16) | XS(8) | XI(8), contiguous for one memset
    float* XL = ACC;
    float* XS = ACC + (size_t)n * 16;
    float* XI = ACC + (size_t)n * 24;
    float* recip = (float*)carve((size_t)N_REL * n * 4);
    int* cnt_all = (int*)carve((size_t)N_REL * n * 4);
    int* rowptr  = (int*)carve((size_t)(n + 1) * 4);
    int* cursor  = (int*)carve((size_t)n * 4);
    int* partial = (int*)carve((size_t)SB * 4);
    int* col0    = (int*)carve((size_t)E0 * 4);

    // ---- counts (all relations) + zero accumulators ----
    int B0 = (E0 + 255) / 256, B1 = (E1 + 255) / 256, B2 = (E2 + 255) / 256, B3 = (E3 + 255) / 256;
    int4 E4   = { E0, E1, E2, E3 };
    int4 boff = { 0, B0, B0 + B1, B0 + B1 + B2 };
    hipMemsetAsync(cnt_all, 0, (size_t)N_REL * n * sizeof(int), stream);
    hipMemsetAsync(ACC, 0, (size_t)n * 32 * sizeof(float), stream);
    k_count_all<<<B0 + B1 + B2 + B3, 256, 0, stream>>>(e_sp, e_fl, e_fs, e_in, E4, boff, cnt_all, n);

    // ---- spatial CSR ----
    k_scan1<<<SB, 256, 0, stream>>>(cnt_all, n, partial);
    k_scan2<<<1, 64, 0, stream>>>(partial, rowptr, n, E0);
    k_scan3<<<SB, 256, 0, stream>>>(cnt_all, partial, rowptr, cursor, recip, n);
    k_recip123<<<(3 * n + 255) / 256, 256, 0, stream>>>(cnt_all, recip, n);
    k_fill<<<B0, 256, 0, stream>>>(e_sp, E0, cursor, col0);

    const float* r0 = recip;
    const float* r1 = recip + (size_t)n;
    const float* r2 = recip + 2 * (size_t)n;
    const float* r3 = recip + 3 * (size_t)n;

    // ---- x_int encoder (MFMA) ----
    k_encmfma<<<(n + 63) / 64, 256, 0, stream>>>(x_int, W_int, b_int, hb_a, n);

    // ---- static relations: push-scatter raw x, then fused small GEMM -> stat (bf16) ----
    int SB1 = (E1 + 15) / 16, SB2 = (E2 + 31) / 32, SB3 = (E3 + 31) / 32;
    k_scatx_all<<<SB1 + SB2 + SB3, 256, 0, stream>>>(e_fl, e_fs, e_in, x_lane, x_sens, x_inj,
                                                     E1, E2, E3, SB1, SB1 + SB2, XL, XS, XI);
    k_stat<<<(n + 7) / 8, 256, 0, stream>>>(XL, XS, XI, W_lane, W_sens, W_inj,
                                            b_lane, b_sens, b_inj, r1, r2, r3, statb, n);

    // ---- 3 layers ----
    const int spmm_grid = (n + 15) / 16;
    const int layer_grid = (n + 63) / 64;
    unsigned short* cur = hb_a;
    unsigned short* nxt = hb_b;
    for (int l = 0; l < 3; ++l) {
        k_spmm<<<spmm_grid, 256, 0, stream>>>(cur, rowptr, col0, r0, statb, aggb, n);
        const float* Ws = self_W + (size_t)l * H * H;
        const float* Wr = rel_W  + (size_t)l * H * H;
        const float* bb = self_b + (size_t)l * H;
        if (l == 2)
            k_layer<1><<<layer_grid, 256, 0, stream>>>(cur, aggb, Ws, Wr, bb, nullptr, out, n);
        else
            k_layer<0><<<layer_grid, 256, 0, stream>>>(cur, aggb, Ws, Wr, bb, nxt, nullptr, n);
        unsigned short* t = cur; cur = nxt; nxt = t;
    }
}

// Round 8
// 371.426 us; speedup vs baseline: 1.4871x; 1.0410x over previous
//
#include <hip/hip_runtime.h>
#include <hip/hip_bf16.h>
#include <math.h>

#define H 128
#define N_REL 4
#define SB 64   // scan blocks (spatial relation)

typedef float f32x4 __attribute__((ext_vector_type(4)));
typedef __bf16 bf16x8 __attribute__((ext_vector_type(8)));

__device__ __forceinline__ unsigned short f2bf(float f) {
    return __builtin_bit_cast(unsigned short, (__bf16)f);
}
__device__ __forceinline__ unsigned pack2(float lo, float hi) {
    return (unsigned)f2bf(lo) | ((unsigned)f2bf(hi) << 16);
}
__device__ __forceinline__ void acc2(unsigned u, float& a, float& b) {
    union { unsigned u; float f; } x, y;
    x.u = u << 16; y.u = u & 0xffff0000u;
    a += x.f; b += y.f;
}
__device__ __forceinline__ float bflo(unsigned u) {
    union { unsigned u; float f; } x; x.u = u << 16; return x.f;
}
__device__ __forceinline__ float bfhi(unsigned u) {
    union { unsigned u; float f; } x; x.u = u & 0xffff0000u; return x.f;
}

// ---------------- spatial count + per-edge sequence (one atomic pass) ----------------
__global__ __launch_bounds__(256) void k_count0(const int* __restrict__ s0, int E0,
                                                int* __restrict__ cnt, int* __restrict__ seq)
{
    int e = blockIdx.x * 256 + threadIdx.x;
    if (e >= E0) return;
    seq[e] = atomicAdd(&cnt[s0[E0 + e]], 1);
}

// ---------------- 3-phase scan (spatial) ----------------
__global__ __launch_bounds__(256) void k_scan1(const int* __restrict__ cnt, int n,
                                               int* __restrict__ partial)
{
    int blk = blockIdx.x;
    int chunk = (n + SB - 1) / SB;
    int lo = blk * chunk, hi = min(lo + chunk, n);
    int s = 0;
    for (int i = lo + threadIdx.x; i < hi; i += 256) s += cnt[i];
    __shared__ int sh[256];
    sh[threadIdx.x] = s; __syncthreads();
    for (int d = 128; d; d >>= 1) {
        if (threadIdx.x < d) sh[threadIdx.x] += sh[threadIdx.x + d];
        __syncthreads();
    }
    if (threadIdx.x == 0) partial[blk] = sh[0];
}

__global__ __launch_bounds__(64) void k_scan2(int* __restrict__ partial,
                                              int* __restrict__ rowptr, int n, int E0)
{
    int lane = threadIdx.x;
    int v = partial[lane];
    int inc = v;
    for (int d = 1; d < 64; d <<= 1) {
        int t = __shfl_up(inc, d);
        if (lane >= d) inc += t;
    }
    partial[lane] = inc - v;
    if (lane == 0) rowptr[n] = E0;
}

__global__ __launch_bounds__(256) void k_scan3(const int* __restrict__ cnt,
                                               const int* __restrict__ partial,
                                               int* __restrict__ rowptr,
                                               float* __restrict__ recip, int n)
{
    int blk = blockIdx.x;
    int chunk = (n + SB - 1) / SB;
    int lo = blk * chunk, hi = min(lo + chunk, n);
    int per = (chunk + 255) >> 8;
    int tlo = min(lo + threadIdx.x * per, hi);
    int thi = min(tlo + per, hi);
    int s = 0;
    for (int i = tlo; i < thi; ++i) s += cnt[i];
    __shared__ int sh[256];
    sh[threadIdx.x] = s; __syncthreads();
    for (int d = 1; d < 256; d <<= 1) {
        int t = (threadIdx.x >= d) ? sh[threadIdx.x - d] : 0;
        __syncthreads();
        sh[threadIdx.x] += t;
        __syncthreads();
    }
    int run = partial[blk] + sh[threadIdx.x] - s;
    for (int i = tlo; i < thi; ++i) {
        int c = cnt[i];
        rowptr[i] = run;
        recip[i] = (c > 0) ? 1.0f / (float)c : 0.0f;
        run += c;
    }
}

// fill via precomputed sequence: no atomics
__global__ __launch_bounds__(256) void k_fill_seq(const int* __restrict__ s0, int E0,
                                                  const int* __restrict__ rowptr,
                                                  const int* __restrict__ seq,
                                                  int* __restrict__ col)
{
    int e = blockIdx.x * 256 + threadIdx.x;
    if (e >= E0) return;
    int t = s0[E0 + e];
    col[rowptr[t] + seq[e]] = s0[e];
}

// ---------------- static relations: push-scatter of raw x + f32 counts (L3-resident) ----------------
__global__ __launch_bounds__(256) void k_scatx_all(
    const int* __restrict__ s1, const int* __restrict__ s2, const int* __restrict__ s3,
    const float* __restrict__ xL, const float* __restrict__ xS, const float* __restrict__ xI,
    int E1, int E2, int E3, int b1, int b2,
    float* __restrict__ XL, float* __restrict__ XS, float* __restrict__ XI,
    float* __restrict__ cL, float* __restrict__ cS, float* __restrict__ cI)
{
    int b = blockIdx.x;
    if (b < b1) {
        int e = b * 16 + (threadIdx.x >> 4);
        if (e >= E1) return;
        int d = threadIdx.x & 15;
        int src = s1[e], tgt = s1[E1 + e];
        unsafeAtomicAdd(&XL[(size_t)tgt * 16 + d], xL[(size_t)src * 16 + d]);
        if (d == 0) unsafeAtomicAdd(&cL[tgt], 1.0f);
    } else if (b < b2) {
        b -= b1;
        int e = b * 32 + (threadIdx.x >> 3);
        if (e >= E2) return;
        int d = threadIdx.x & 7;
        int src = s2[e], tgt = s2[E2 + e];
        unsafeAtomicAdd(&XS[(size_t)tgt * 8 + d], xS[(size_t)src * 8 + d]);
        if (d == 0) unsafeAtomicAdd(&cS[tgt], 1.0f);
    } else {
        b -= b2;
        int e = b * 32 + (threadIdx.x >> 3);
        if (e >= E3) return;
        int d = threadIdx.x & 7;
        int src = s3[e], tgt = s3[E3 + e];
        unsafeAtomicAdd(&XI[(size_t)tgt * 8 + d], xI[(size_t)src * 8 + d]);
        if (d == 0) unsafeAtomicAdd(&cI[tgt], 1.0f);
    }
}

// ---------------- MFMA encoder for x_int (K=32, one MFMA step) ----------------
__global__ __launch_bounds__(256) void k_encmfma(const float* __restrict__ x,
                                                 const float* __restrict__ W,
                                                 const float* __restrict__ b,
                                                 unsigned short* __restrict__ h, int n)
{
    __shared__ __align__(16) char WB[128 * 80];
    int tid = threadIdx.x;
    {
        int c = tid & 127, khalf = tid >> 7;
        for (int kk = 0; kk < 16; ++kk) {
            int k = khalf * 16 + kk;
            *(unsigned short*)(WB + c * 80 + k * 2) = f2bf(W[(size_t)k * H + c]);
        }
    }
    int lane = tid & 63, wv = tid >> 6;
    int r16 = lane & 15, kgrp = lane >> 4;
    int rowbase = blockIdx.x * 64 + wv * 16;
    int arow = rowbase + r16; if (arow >= n) arow = n - 1;
    const float* xr = x + (size_t)arow * 32 + kgrp * 8;
    float4 xa = *(const float4*)xr, xb = *(const float4*)(xr + 4);
    bf16x8 af;
    af[0] = (__bf16)xa.x; af[1] = (__bf16)xa.y; af[2] = (__bf16)xa.z; af[3] = (__bf16)xa.w;
    af[4] = (__bf16)xb.x; af[5] = (__bf16)xb.y; af[6] = (__bf16)xb.z; af[7] = (__bf16)xb.w;
    __syncthreads();
#pragma unroll
    for (int ct = 0; ct < 8; ++ct) {
        int c = ct * 16 + r16;
        bf16x8 bf = *(const bf16x8*)(WB + c * 80 + kgrp * 16);
        f32x4 acc = { 0.f, 0.f, 0.f, 0.f };
        acc = __builtin_amdgcn_mfma_f32_16x16x32_bf16(af, bf, acc, 0, 0, 0);
        float bb = b[c];
#pragma unroll
        for (int i = 0; i < 4; ++i) {
            int grow = rowbase + kgrp * 4 + i;
            if (grow < n) h[(size_t)grow * H + c] = f2bf(acc[i] + bb);
        }
    }
}

// ---------------- stat(bf16) = (XL/cL)@WL + (XS/cS)@WS + (XI/cI)@WI + masked biases ----------------
__global__ __launch_bounds__(256) void k_stat(
    const float* __restrict__ XL, const float* __restrict__ XS, const float* __restrict__ XI,
    const float* __restrict__ WL, const float* __restrict__ WSn, const float* __restrict__ WI,
    const float* __restrict__ bL, const float* __restrict__ bS, const float* __restrict__ bI,
    const float* __restrict__ cLp, const float* __restrict__ cSp, const float* __restrict__ cIp,
    unsigned short* __restrict__ statb, int n)
{
    __shared__ float Wc[32][128];
    __shared__ float xs[8][32];
    __shared__ float msk[8][3];
    int t = threadIdx.x;
    for (int i = t; i < 16 * 128; i += 256) Wc[i >> 7][i & 127] = WL[i];
    for (int i = t; i < 8 * 128; i += 256)  Wc[16 + (i >> 7)][i & 127] = WSn[i];
    for (int i = t; i < 8 * 128; i += 256)  Wc[24 + (i >> 7)][i & 127] = WI[i];
    {
        int rr = t >> 5, k = t & 31;
        int rrow = blockIdx.x * 8 + rr; if (rrow >= n) rrow = n - 1;
        float v;
        if (k < 16) {
            float c = cLp[rrow];
            float r = (c > 0.f) ? 1.0f / c : 0.0f;
            v = XL[(size_t)rrow * 16 + k] * r;
            if (k == 0) msk[rr][0] = (c > 0.f) ? 1.f : 0.f;
        } else if (k < 24) {
            float c = cSp[rrow];
            float r = (c > 0.f) ? 1.0f / c : 0.0f;
            v = XS[(size_t)rrow * 8 + (k - 16)] * r;
            if (k == 16) msk[rr][1] = (c > 0.f) ? 1.f : 0.f;
        } else {
            float c = cIp[rrow];
            float r = (c > 0.f) ? 1.0f / c : 0.0f;
            v = XI[(size_t)rrow * 8 + (k - 24)] * r;
            if (k == 24) msk[rr][2] = (c > 0.f) ? 1.f : 0.f;
        }
        xs[rr][k] = v;
    }
    __syncthreads();
    int rl = t >> 5, c4 = (t & 31) << 2;
    int row = blockIdx.x * 8 + rl;
    float a0 = 0.f, a1 = 0.f, a2 = 0.f, a3 = 0.f;
#pragma unroll
    for (int k = 0; k < 32; ++k) {
        float xv = xs[rl][k];
        a0 += xv * Wc[k][c4 + 0]; a1 += xv * Wc[k][c4 + 1];
        a2 += xv * Wc[k][c4 + 2]; a3 += xv * Wc[k][c4 + 3];
    }
    if (row < n) {
        float mL = msk[rl][0], mS = msk[rl][1], mI = msk[rl][2];
        uint2 res;
        res.x = pack2(a0 + mL * bL[c4 + 0] + mS * bS[c4 + 0] + mI * bI[c4 + 0],
                      a1 + mL * bL[c4 + 1] + mS * bS[c4 + 1] + mI * bI[c4 + 1]);
        res.y = pack2(a2 + mL * bL[c4 + 2] + mS * bS[c4 + 2] + mI * bI[c4 + 2],
                      a3 + mL * bL[c4 + 3] + mS * bS[c4 + 3] + mI * bI[c4 + 3]);
        *(uint2*)(statb + (size_t)row * H + c4) = res;
    }
}

// ---------------- spatial SpMM: aggb = bf16(mean(hb_nbr) + statb) ----------------
__global__ __launch_bounds__(256) void k_spmm(const unsigned short* __restrict__ hsrc,
                                              const int* __restrict__ rowptr,
                                              const int* __restrict__ col,
                                              const float* __restrict__ recip,
                                              const unsigned short* __restrict__ statb,
                                              unsigned short* __restrict__ aggout, int n)
{
    int row = blockIdx.x * 16 + (threadIdx.x >> 4);
    if (row >= n) return;
    int q = (threadIdx.x & 15) << 3;   // 8 bf16 per lane
    int beg = rowptr[row], end = rowptr[row + 1];

    float a0 = 0.f, a1 = 0.f, a2 = 0.f, a3 = 0.f, a4 = 0.f, a5 = 0.f, a6 = 0.f, a7 = 0.f;
    int e = beg;
    for (; e + 4 <= end; e += 4) {
        int s0 = col[e], s1 = col[e + 1], s2 = col[e + 2], s3 = col[e + 3];
        uint4 v0 = *(const uint4*)(hsrc + (size_t)s0 * H + q);
        uint4 v1 = *(const uint4*)(hsrc + (size_t)s1 * H + q);
        uint4 v2 = *(const uint4*)(hsrc + (size_t)s2 * H + q);
        uint4 v3 = *(const uint4*)(hsrc + (size_t)s3 * H + q);
        acc2(v0.x, a0, a1); acc2(v0.y, a2, a3); acc2(v0.z, a4, a5); acc2(v0.w, a6, a7);
        acc2(v1.x, a0, a1); acc2(v1.y, a2, a3); acc2(v1.z, a4, a5); acc2(v1.w, a6, a7);
        acc2(v2.x, a0, a1); acc2(v2.y, a2, a3); acc2(v2.z, a4, a5); acc2(v2.w, a6, a7);
        acc2(v3.x, a0, a1); acc2(v3.y, a2, a3); acc2(v3.z, a4, a5); acc2(v3.w, a6, a7);
    }
    for (; e < end; ++e) {
        uint4 v0 = *(const uint4*)(hsrc + (size_t)col[e] * H + q);
        acc2(v0.x, a0, a1); acc2(v0.y, a2, a3); acc2(v0.z, a4, a5); acc2(v0.w, a6, a7);
    }

    float r = recip[row];
    size_t o = (size_t)row * H + q;
    uint4 sv = *(const uint4*)(statb + o);
    uint4 w;
    w.x = pack2(a0 * r + bflo(sv.x), a1 * r + bfhi(sv.x));
    w.y = pack2(a2 * r + bflo(sv.y), a3 * r + bfhi(sv.y));
    w.z = pack2(a4 * r + bflo(sv.z), a5 * r + bfhi(sv.z));
    w.w = pack2(a6 * r + bflo(sv.w), a7 * r + bfhi(sv.w));
    *(uint4*)(aggout + o) = w;
}

// ---------------- MFMA layer: elu([h|agg] @ [Wself;Wrel] + b) ----------------
template<int LAST>
__global__ __launch_bounds__(256) void k_layer(const unsigned short* __restrict__ hb,
                                               const unsigned short* __restrict__ aggb,
                                               const float* __restrict__ Ws,
                                               const float* __restrict__ Wr,
                                               const float* __restrict__ bias,
                                               unsigned short* __restrict__ hbout,
                                               float* __restrict__ fout, int n)
{
    __shared__ __align__(16) char BT[128 * 256 * 2];

    int tid = threadIdx.x;
    {
        int c = tid & 127, half = tid >> 7;
        for (int kc = half; kc < 32; kc += 2) {
            int kk0 = kc * 8;
            const float* Wsrc = (kk0 < 128) ? (Ws + (size_t)kk0 * H + c)
                                            : (Wr + (size_t)(kk0 - 128) * H + c);
            bf16x8 pack;
#pragma unroll
            for (int j = 0; j < 8; ++j) pack[j] = (__bf16)Wsrc[(size_t)j * H];
            int woff = c * 512 + ((kc * 16) ^ ((c & 7) << 4));
            *(bf16x8*)(BT + woff) = pack;
        }
    }

    int lane = tid & 63, wv = tid >> 6;
    int r16 = lane & 15, kgrp = lane >> 4;
    int rowbase = blockIdx.x * 64 + wv * 16;
    int arow = rowbase + r16; if (arow >= n) arow = n - 1;

    bf16x8 afrag[8];
#pragma unroll
    for (int ks = 0; ks < 8; ++ks) {
        int k0 = ks * 32 + kgrp * 8;
        const unsigned short* src = (k0 < 128) ? (hb + (size_t)arow * H + k0)
                                               : (aggb + (size_t)arow * H + (k0 - 128));
        afrag[ks] = *(const bf16x8*)src;
    }
    __syncthreads();

#pragma unroll
    for (int ct = 0; ct < 8; ++ct) {
        int c = ct * 16 + r16;
        f32x4 acc = { 0.f, 0.f, 0.f, 0.f };
#pragma unroll
        for (int ks = 0; ks < 8; ++ks) {
            int kbyte = ks * 64 + kgrp * 16;
            int off = c * 512 + (kbyte ^ ((c & 7) << 4));
            bf16x8 bfrag = *(const bf16x8*)(BT + off);
            acc = __builtin_amdgcn_mfma_f32_16x16x32_bf16(afrag[ks], bfrag, acc, 0, 0, 0);
        }
        float bb = bias[c];
#pragma unroll
        for (int i = 0; i < 4; ++i) {
            int grow = rowbase + kgrp * 4 + i;
            if (grow < n) {
                float v = acc[i] + bb;
                v = (v > 0.f) ? v : (expf(v) - 1.f);
                if (LAST) fout[(size_t)grow * H + c] = v;
                else      hbout[(size_t)grow * H + c] = f2bf(v);
            }
        }
    }
}

extern "C" void kernel_launch(void* const* d_in, const int* in_sizes, int n_in,
                              void* d_out, int out_size, void* d_ws, size_t ws_size,
                              hipStream_t stream)
{
    const float* x_int  = (const float*)d_in[0];
    const float* x_lane = (const float*)d_in[1];
    const float* x_sens = (const float*)d_in[2];
    const float* x_inj  = (const float*)d_in[3];
    const int*   e_sp   = (const int*)d_in[4];
    const int*   e_fl   = (const int*)d_in[5];
    const int*   e_fs   = (const int*)d_in[6];
    const int*   e_in   = (const int*)d_in[7];
    const float* W_int  = (const float*)d_in[8];
    const float* b_int  = (const float*)d_in[9];
    const float* W_lane = (const float*)d_in[10];
    const float* b_lane = (const float*)d_in[11];
    const float* W_sens = (const float*)d_in[12];
    const float* b_sens = (const float*)d_in[13];
    const float* W_inj  = (const float*)d_in[14];
    const float* b_inj  = (const float*)d_in[15];
    const float* self_W = (const float*)d_in[16];
    const float* self_b = (const float*)d_in[17];
    const float* rel_W  = (const float*)d_in[18];

    const int n = in_sizes[0] / 32;
    const int E0 = in_sizes[4] / 2, E1 = in_sizes[5] / 2, E2 = in_sizes[6] / 2, E3 = in_sizes[7] / 2;

    float* out = (float*)d_out;

    // ---- workspace carve ----
    char* base = (char*)d_ws;
    size_t off = 0;
    auto carve = [&](size_t bytes) { char* p = base + off; off += (bytes + 15) & ~(size_t)15; return p; };
    unsigned short* hb_a  = (unsigned short*)carve((size_t)n * H * 2);
    unsigned short* hb_b  = (unsigned short*)carve((size_t)n * H * 2);
    unsigned short* aggb  = (unsigned short*)carve((size_t)n * H * 2);
    unsigned short* statb = (unsigned short*)carve((size_t)n * H * 2);
    // zero-init region: ACC (n*32 f32) | CNTf (3n f32) | cnt0 (n int)
    float* ZERO  = (float*)carve((size_t)n * 36 * 4);
    float* XL   = ZERO;
    float* XS   = ZERO + (size_t)n * 16;
    float* XI   = ZERO + (size_t)n * 24;
    float* CNT1 = ZERO + (size_t)n * 32;
    float* CNT2 = ZERO + (size_t)n * 33;
    float* CNT3 = ZERO + (size_t)n * 34;
    int*   cnt0 = (int*)(ZERO + (size_t)n * 35);
    float* recip0 = (float*)carve((size_t)n * 4);
    int* rowptr  = (int*)carve((size_t)(n + 1) * 4);
    int* partial = (int*)carve((size_t)SB * 4);
    int* seq     = (int*)carve((size_t)E0 * 4);
    int* col0    = (int*)carve((size_t)E0 * 4);

    int B0 = (E0 + 255) / 256;

    // ---- zero-init + spatial count(+seq) ----
    hipMemsetAsync(ZERO, 0, (size_t)n * 36 * sizeof(float), stream);
    k_count0<<<B0, 256, 0, stream>>>(e_sp, E0, cnt0, seq);

    // ---- spatial CSR ----
    k_scan1<<<SB, 256, 0, stream>>>(cnt0, n, partial);
    k_scan2<<<1, 64, 0, stream>>>(partial, rowptr, n, E0);
    k_scan3<<<SB, 256, 0, stream>>>(cnt0, partial, rowptr, recip0, n);
    k_fill_seq<<<B0, 256, 0, stream>>>(e_sp, E0, rowptr, seq, col0);

    // ---- x_int encoder (MFMA) ----
    k_encmfma<<<(n + 63) / 64, 256, 0, stream>>>(x_int, W_int, b_int, hb_a, n);

    // ---- static relations: push-scatter raw x (+f32 counts), then fused GEMM -> stat ----
    int SB1 = (E1 + 15) / 16, SB2 = (E2 + 31) / 32, SB3 = (E3 + 31) / 32;
    k_scatx_all<<<SB1 + SB2 + SB3, 256, 0, stream>>>(e_fl, e_fs, e_in, x_lane, x_sens, x_inj,
                                                     E1, E2, E3, SB1, SB1 + SB2,
                                                     XL, XS, XI, CNT1, CNT2, CNT3);
    k_stat<<<(n + 7) / 8, 256, 0, stream>>>(XL, XS, XI, W_lane, W_sens, W_inj,
                                            b_lane, b_sens, b_inj, CNT1, CNT2, CNT3, statb, n);

    // ---- 3 layers ----
    const int spmm_grid = (n + 15) / 16;
    const int layer_grid = (n + 63) / 64;
    unsigned short* cur = hb_a;
    unsigned short* nxt = hb_b;
    for (int l = 0; l < 3; ++l) {
        k_spmm<<<spmm_grid, 256, 0, stream>>>(cur, rowptr, col0, recip0, statb, aggb, n);
        const float* Ws = self_W + (size_t)l * H * H;
        const float* Wr = rel_W  + (size_t)l * H * H;
        const float* bb = self_b + (size_t)l * H;
        if (l == 2)
            k_layer<1><<<layer_grid, 256, 0, stream>>>(cur, aggb, Ws, Wr, bb, nullptr, out, n);
        else
            k_layer<0><<<layer_grid, 256, 0, stream>>>(cur, aggb, Ws, Wr, bb, nxt, nullptr, n);
        unsigned short* t = cur; cur = nxt; nxt = t;
    }
}